// Round 4
// baseline (381.609 us; speedup 1.0000x reference)
//
#include <hip/hip_runtime.h>

// LIF spike scan, R3: R2's coalesced whole-row wave tiles + software-pipelined
// grid-stride loop (register prefetch of the next tile behind scan+store).
// x/out: [524288 neurons][T=100] fp32 row-major.
//
// R2 recap: wave owns 64 contiguous rows (25.6 KB flat region); 25 perfect
// 1024-B wave loads; transpose via LDS tile [25 timegroup][65 pad] float4;
// scan conflict-free; gather + 25 coalesced stores. ~100 us (~4.2 TB/s).
// R3 insight (from fillBuffer: 6.5 TB/s at 10% occupancy): the gap is memory-
// issue DUTY CYCLE, not occupancy. So: persistent blocks loop over tiles;
// at iteration top, issue the NEXT tile's 25 global loads into registers.
// Their vmcnt waits land only at the end-of-iteration ds_write scatter, so
// ~25 KB/wave stays in flight behind the whole scan+store phase.
//
// Synchronization (single-wave blocks, no __syncthreads — it would drain
// vmcnt(0) and kill the pipeline):
//  - scatter(t) -> scan(t) reads  : explicit lgkmcnt(0)-only wait, 0xC07F
//    (vmcnt=ignore(63), expcnt=ignore, lgkm=0), placed AFTER next loads issue
//  - scan writes -> gather reads, gather reads -> scatter(t+1) writes:
//    same-wave DS ops execute in order (in-order LDS pipe)
//  - load data -> ds_write, ds_read data -> global_store: register deps,
//    compiler inserts fine-grained waitcnts
//
// Numerics: output is a threshold compare; must match numpy's rounding
// sequence mem=(mem*DECAY)*(1-spike)+xi bit-exactly. spike is exactly 0/1,
// so  mem = spike ? xi : __fadd_rn(__fmul_rn(mem,DECAY), xi)  is
// bit-identical (mul by 1.0 / add of -0.0 are exact identities). Verified
// absmax=0 in R1/R2.

#define THRESH 0.5f
#define DECAY  0.2f

constexpr int T        = 100;
constexpr int ROWS     = 64;            // neurons per wave/block
constexpr int F4_ROW   = T / 4;         // 25 float4 per row
constexpr int F4_TILE  = ROWS * F4_ROW; // 1600 float4 per tile (25.6 KB)
constexpr int K        = F4_TILE / 64;  // 25 coalesced wave ops per phase
constexpr int STRIDE   = ROWS + 1;      // 65 f4 LDS row stride (de-conflict)
constexpr int GRID     = 1536;          // 6 blocks/CU x 256 CU (LDS-capped)

// s_waitcnt imm: vmcnt=63 (ignore), expcnt=7 (ignore), lgkmcnt=0
#define WAIT_LGKM0() __builtin_amdgcn_s_waitcnt(0xC07F)

__global__ __launch_bounds__(64) void lif_kernel(const float* __restrict__ x,
                                                 float* __restrict__ out,
                                                 int ntiles) {
    __shared__ float4 tile[F4_ROW * STRIDE];  // 26 KB -> 6 blocks/CU

    const int l = threadIdx.x;
    const float4* xf = reinterpret_cast<const float4*>(x);
    float4*       of = reinterpret_cast<float4*>(out);

    int t = blockIdx.x;
    if (t >= ntiles) return;

    float4 v[K];

    // ---- prologue: load + scatter tile t ----
    {
        const float4* src = xf + (size_t)t * F4_TILE;
#pragma unroll
        for (int k = 0; k < K; ++k) v[k] = src[k * 64 + l];
#pragma unroll
        for (int k = 0; k < K; ++k) {
            int f = k * 64 + l;
            tile[(f % F4_ROW) * STRIDE + (f / F4_ROW)] = v[k];
        }
    }

    for (; t < ntiles; ) {
        const int tn = t + GRID;
        const bool have_next = (tn < ntiles);

        // ---- prefetch next tile into registers (vmcnt waits land at the
        //      scatter at the END of this iteration -> overlaps scan+store) --
        if (have_next) {
            const float4* src = xf + (size_t)tn * F4_TILE;
#pragma unroll
            for (int k = 0; k < K; ++k) v[k] = src[k * 64 + l];
        }

        // ensure scatter of current tile is committed before scan reads
        WAIT_LGKM0();

        // ---- scan: lane l owns row l; tile[g][l] is conflict-free ----
        float mem = 0.0f, spike = 0.0f;
#pragma unroll
        for (int g = 0; g < F4_ROW; ++g) {
            float4 u = tile[g * STRIDE + l];
            float4 s;
#define STEP(comp)                                                            \
            {                                                                 \
                float leak = __fmul_rn(mem, DECAY);                           \
                mem = (spike != 0.0f) ? u.comp : __fadd_rn(leak, u.comp);     \
                spike = (mem > THRESH) ? 1.0f : 0.0f;                         \
                s.comp = spike;                                               \
            }
            STEP(x) STEP(y) STEP(z) STEP(w)
#undef STEP
            tile[g * STRIDE + l] = s;  // in-place, conflict-free
        }

        // ---- gather + 25 coalesced stores (reads see scan writes: in-order
        //      DS pipe; store data dep -> compiler lgkm waits) ----
        {
            float4* dst = of + (size_t)t * F4_TILE;
#pragma unroll
            for (int k = 0; k < K; ++k) {
                int f = k * 64 + l;
                dst[k * 64 + l] = tile[(f % F4_ROW) * STRIDE + (f / F4_ROW)];
            }
        }

        // ---- scatter next tile (ds_writes ordered after gather ds_reads by
        //      the in-order DS pipe; vmcnt waits for v[k] inserted here) ----
        if (have_next) {
#pragma unroll
            for (int k = 0; k < K; ++k) {
                int f = k * 64 + l;
                tile[(f % F4_ROW) * STRIDE + (f / F4_ROW)] = v[k];
            }
        }

        t = tn;
    }
}

extern "C" void kernel_launch(void* const* d_in, const int* in_sizes, int n_in,
                              void* d_out, int out_size, void* d_ws, size_t ws_size,
                              hipStream_t stream) {
    const float* x   = (const float*)d_in[0];
    float*       out = (float*)d_out;

    int n_neurons = in_sizes[0] / T;      // 524288
    int ntiles    = n_neurons / ROWS;     // 8192 tiles of 64 rows

    lif_kernel<<<GRID, ROWS, 0, stream>>>(x, out, ntiles);
}

// Round 6
// 336.017 us; speedup vs baseline: 1.1357x; 1.1357x over previous
//
#include <hip/hip_runtime.h>

// LIF spike scan, R5: R3's pipelined coalesced wave tiles + NONTEMPORAL I/O.
// (R4 failed to compile: __builtin_nontemporal_* rejects HIP_vector_type;
//  use a native clang ext_vector float4 instead. No structural change.)
// x/out: [524288 neurons][T=100] fp32 row-major.
//
// R3 post-mortem: WRITE_SIZE was 2.0x ideal (409 GB vs 210 MB) -> ~+43 us of
// write-path churn (write-allocate + dirty 0xAA-poison lines in L3 double-
// evicted during our dispatch). Input/output have ZERO temporal reuse, so all
// global I/O is nontemporal (global_load/store_dwordx4 nt): stores stream to
// HBM without allocating, loads don't thrash L3.
//
// Structure (R2/R3, proven absmax=0): wave owns 64 contiguous rows = one
// 25.6-KB flat region; 25 perfect 1024-B wave loads; transpose via LDS tile
// [25 timegroup][65 pad] float4 (scan access conflict-free); persistent
// blocks grid-stride over tiles, prefetching the next tile's 25 loads into
// registers so ~25 KB/wave stays in flight behind scan+store (memory-issue
// duty cycle, per fillBuffer: 6.5 TB/s at 10% occupancy).
//
// Sync (single-wave blocks, no __syncthreads -- would drain vmcnt and kill
// the pipeline): scatter->scan covered by lgkmcnt(0)-only wait (0xC07F,
// vmcnt/exp ignored) placed AFTER next loads issue; scan->gather and
// gather->scatter(t+1) covered by the in-order DS pipe; load->ds_write and
// ds_read->store are register deps (compiler inserts fine-grained waitcnts).
//
// Numerics: output is a threshold compare; must match numpy's rounding
// sequence mem=(mem*DECAY)*(1-spike)+xi bit-exactly. spike is exactly 0/1,
// so  mem = spike ? xi : __fadd_rn(__fmul_rn(mem,DECAY), xi)  is
// bit-identical. Verified absmax=0 in R1-R3.

#define THRESH 0.5f
#define DECAY  0.2f

typedef float fx4 __attribute__((ext_vector_type(4)));  // native vec4 for nt builtins

constexpr int T        = 100;
constexpr int ROWS     = 64;            // neurons per wave/block
constexpr int F4_ROW   = T / 4;         // 25 float4 per row
constexpr int F4_TILE  = ROWS * F4_ROW; // 1600 float4 per tile (25.6 KB)
constexpr int K        = F4_TILE / 64;  // 25 coalesced wave ops per phase
constexpr int STRIDE   = ROWS + 1;      // 65 f4 LDS row stride (de-conflict)
constexpr int GRID     = 1536;          // 6 blocks/CU x 256 CU (LDS-capped)

// s_waitcnt imm: vmcnt=63 (ignore), expcnt=7 (ignore), lgkmcnt=0
#define WAIT_LGKM0() __builtin_amdgcn_s_waitcnt(0xC07F)

__global__ __launch_bounds__(64) void lif_kernel(const float* __restrict__ x,
                                                 float* __restrict__ out,
                                                 int ntiles) {
    __shared__ fx4 tile[F4_ROW * STRIDE];  // 26 KB -> 6 blocks/CU

    const int l = threadIdx.x;
    const fx4* xf = reinterpret_cast<const fx4*>(x);
    fx4*       of = reinterpret_cast<fx4*>(out);

    int t = blockIdx.x;
    if (t >= ntiles) return;

    fx4 v[K];

    // ---- prologue: load + scatter tile t ----
    {
        const fx4* src = xf + (size_t)t * F4_TILE;
#pragma unroll
        for (int k = 0; k < K; ++k)
            v[k] = __builtin_nontemporal_load(src + k * 64 + l);
#pragma unroll
        for (int k = 0; k < K; ++k) {
            int f = k * 64 + l;
            tile[(f % F4_ROW) * STRIDE + (f / F4_ROW)] = v[k];
        }
    }

    for (; t < ntiles; ) {
        const int tn = t + GRID;
        const bool have_next = (tn < ntiles);

        // ---- prefetch next tile (nt loads; vmcnt waits land only at the
        //      end-of-iteration scatter -> overlaps scan+store) ----
        if (have_next) {
            const fx4* src = xf + (size_t)tn * F4_TILE;
#pragma unroll
            for (int k = 0; k < K; ++k)
                v[k] = __builtin_nontemporal_load(src + k * 64 + l);
        }

        // ensure scatter of current tile is committed before scan reads
        WAIT_LGKM0();

        // ---- scan: lane l owns row l; tile[g][l] is conflict-free ----
        float mem = 0.0f, spike = 0.0f;
#pragma unroll
        for (int g = 0; g < F4_ROW; ++g) {
            fx4 u = tile[g * STRIDE + l];
            fx4 s;
#define STEP(comp)                                                            \
            {                                                                 \
                float leak = __fmul_rn(mem, DECAY);                           \
                mem = (spike != 0.0f) ? u.comp : __fadd_rn(leak, u.comp);     \
                spike = (mem > THRESH) ? 1.0f : 0.0f;                         \
                s.comp = spike;                                               \
            }
            STEP(x) STEP(y) STEP(z) STEP(w)
#undef STEP
            tile[g * STRIDE + l] = s;  // in-place, conflict-free
        }

        // ---- gather + 25 coalesced nt stores (reads see scan writes via
        //      in-order DS pipe; store data dep -> compiler lgkm waits) ----
        {
            fx4* dst = of + (size_t)t * F4_TILE;
#pragma unroll
            for (int k = 0; k < K; ++k) {
                int f = k * 64 + l;
                __builtin_nontemporal_store(
                    tile[(f % F4_ROW) * STRIDE + (f / F4_ROW)],
                    dst + k * 64 + l);
            }
        }

        // ---- scatter next tile (ds_writes ordered after gather ds_reads by
        //      the in-order DS pipe; vmcnt waits for v[k] inserted here) ----
        if (have_next) {
#pragma unroll
            for (int k = 0; k < K; ++k) {
                int f = k * 64 + l;
                tile[(f % F4_ROW) * STRIDE + (f / F4_ROW)] = v[k];
            }
        }

        t = tn;
    }
}

extern "C" void kernel_launch(void* const* d_in, const int* in_sizes, int n_in,
                              void* d_out, int out_size, void* d_ws, size_t ws_size,
                              hipStream_t stream) {
    const float* x   = (const float*)d_in[0];
    float*       out = (float*)d_out;

    int n_neurons = in_sizes[0] / T;      // 524288
    int ntiles    = n_neurons / ROWS;     // 8192 tiles of 64 rows

    lif_kernel<<<GRID, ROWS, 0, stream>>>(x, out, ntiles);
}